// Round 6
// baseline (1248.199 us; speedup 1.0000x reference)
//
#include <hip/hip_runtime.h>

#define NPN   1024            // nodes per slice
#define NB    512             // batch (slices)
#define NE_S  2048            // edges per slice
#define DD    128             // feature dim
#define NN    (NB * NPN)      // 524288 total nodes
#define NE    (NB * NE_S)     // 1048576 total edges

typedef short s16x8 __attribute__((ext_vector_type(8)));
typedef float f32x4 __attribute__((ext_vector_type(4)));

static __device__ __forceinline__ unsigned short f2bf(float f) {
    unsigned u = __builtin_bit_cast(unsigned, f);
    unsigned r = (u + 0x7FFFu + ((u >> 16) & 1u)) >> 16;   // RNE
    return (unsigned short)r;
}
static __device__ __forceinline__ float bf2f(unsigned short h) {
    unsigned u = ((unsigned)h) << 16;
    return __builtin_bit_cast(float, u);
}

// ---------- CSR / degree precompute (layer-invariant) ----------

__global__ void k_count(const int* __restrict__ ei, int* __restrict__ deg) {
    int t = blockIdx.x * 256 + threadIdx.x;          // 0..NE-1
    int b = t >> 11, e = t & (NE_S - 1);
    int col = ei[b * (2 * NE_S) + NE_S + e];
    atomicAdd(&deg[b * NPN + col], 1);
}

__global__ void k_dinv(const int* __restrict__ deg, float* __restrict__ dinv) {
    int i = blockIdx.x * 256 + threadIdx.x;
    dinv[i] = rsqrtf((float)(deg[i] + 1));           // +1 self-loop
}

__global__ __launch_bounds__(1024) void k_scan(const int* __restrict__ deg,
                                               int* __restrict__ coff,
                                               int* __restrict__ cur) {
    __shared__ int s[NPN];
    int b = blockIdx.x, t = threadIdx.x;
    int v = deg[b * NPN + t];
    s[t] = v;
    __syncthreads();
    for (int off = 1; off < NPN; off <<= 1) {
        int add = (t >= off) ? s[t - off] : 0;
        __syncthreads();
        s[t] += add;
        __syncthreads();
    }
    coff[b * NPN + t] = b * NE_S + (s[t] - v);       // exclusive prefix, global offset
    cur[b * NPN + t] = 0;
}

// packed edge meta: .x = src_local | (dst_local<<16), .y = bitcast(norm)
__global__ void k_fill(const int* __restrict__ ei, const float* __restrict__ dinv,
                       const int* __restrict__ coff, int* __restrict__ cur,
                       int2* __restrict__ cmeta) {
    int t = blockIdx.x * 256 + threadIdx.x;
    int b = t >> 11, e = t & (NE_S - 1);
    int r = ei[b * (2 * NE_S) + e];
    int c = ei[b * (2 * NE_S) + NE_S + e];
    int gr = b * NPN + r, gc = b * NPN + c;
    int pos = coff[gc] + atomicAdd(&cur[gc], 1);
    float nw = dinv[gr] * dinv[gc];
    cmeta[pos] = make_int2(r | (c << 16), __builtin_bit_cast(int, nw));
}

// ---------- W pre-transpose + bf16 hi/lo split (per layer, tiny) ----------

__global__ __launch_bounds__(256) void k_wsplit(const float* __restrict__ W,
                                                short* __restrict__ WTh,
                                                short* __restrict__ WTl) {
    int idx = blockIdx.x * 256 + threadIdx.x;        // 0..16383
    int k = idx >> 7, n = idx & 127;
    float f = W[idx];
    unsigned short h = f2bf(f);
    unsigned short l = f2bf(f - bf2f(h));
    WTh[n * DD + k] = (short)h;
    WTl[n * DD + k] = (short)l;
}

// ---------- fused GCN layer: out = relu((A_hat x) @ W + b) ----------
// 512 thr / 8 waves / block; 64x128 output tile; 32 KiB LDS union
//   (4 blocks/CU, 32 waves/CU):
//   phase A: fp32 accumulator sAcc[64][128], de-interleaved cols.
//   phase B: bf16 hi half [0,16K) + lo half [16K,32K), XOR-swizzled.
//   phase C: fp32 result staging [64][128] -> full-cacheline streamed
//            stores (avoids the half-line write-allocate RMW penalty).
// Gather: wave w owns rows w*8..+7 and their contiguous CSR edge range;
// meta broadcast via v_readlane (scalar control), 8 row-loads in flight,
// run-based accumulation (edges dst-sorted) -> LDS add per run.

__global__ __launch_bounds__(512, 8) void k_layer(const float* __restrict__ x,
                                                  unsigned gmask,
                                                  const short* __restrict__ WTh,
                                                  const short* __restrict__ WTl,
                                                  const float* __restrict__ bias,
                                                  const float* __restrict__ dinv,
                                                  const int* __restrict__ coff,
                                                  const int2* __restrict__ cmeta,
                                                  float* __restrict__ out) {
    __shared__ float sBuf[64 * DD];      // 32 KiB union
    float* sAcc = sBuf;
    char*  sH   = (char*)sBuf;           // after repack: hi bytes [0,16K)
    char*  sL   = (char*)sBuf + 16384;   // lo bytes [16K,32K)

    int t = threadIdx.x;
    int wave = t >> 6, lane = t & 63;
    // XCD-aware swizzle: 8192 blocks = 8 XCDs x 1024; 16 consecutive
    // blocks (one slice) land on one XCD -> slice rows L2-hit.
    int wb = (int)((blockIdx.x & 7) * 1024 + (blockIdx.x >> 3));
    int m0 = wb * 64;
    int sbase = (wb >> 4) << 10;         // slice base node

    int n  = lane & 15;
    int kq = lane >> 4;

    // wave's CSR range (scalarized -> uniform control flow)
    int r0g = m0 + wave * 8;
    int eBeg = __builtin_amdgcn_readfirstlane(coff[r0g]);
    int eEnd = __builtin_amdgcn_readfirstlane((r0g + 8 < NN) ? coff[r0g + 8] : NE);

    // ---- B fragments from global (L2-resident 64 KB, loaded once) ----
    const short* bhp = &WTh[(wave * 16 + n) * DD + kq * 8];
    const short* blp = &WTl[(wave * 16 + n) * DD + kq * 8];
    s16x8 bh[4], bl[4];
    #pragma unroll
    for (int ks = 0; ks < 4; ++ks) {
        bh[ks] = *(const s16x8*)(bhp + ks * 32);
        bl[ks] = *(const s16x8*)(blp + ks * 32);
    }

    // ---- self-loop init: rows wave*8..+7, lane covers features 2l,2l+1 ----
    {
        float2 sv[8]; float dvv[8];
        #pragma unroll
        for (int i = 0; i < 8; ++i) {
            int g = m0 + wave * 8 + i;
            dvv[i] = dinv[g];
            sv[i] = *(const float2*)&x[(size_t)((unsigned)g & gmask) * DD + lane * 2];
        }
        #pragma unroll
        for (int i = 0; i < 8; ++i) {
            int row = wave * 8 + i;
            float s = dvv[i] * dvv[i];
            sAcc[row * DD + lane]      = s * sv[i].x;
            sAcc[row * DD + 64 + lane] = s * sv[i].y;
        }
    }
    // no barrier needed: this wave only touches its own 8 rows below

    // ---- edge walk: run-based accumulation, 8 loads in flight ----
    float ax = 0.f, ay = 0.f;
    int curRow = -1;
    for (int c0 = eBeg; c0 < eEnd; c0 += 64) {
        int nC = eEnd - c0; nC = nC > 64 ? 64 : nC;
        // pad lanes: src10=0 (valid row, w=0), dst10=0xFFFF (run-breaker)
        int2 md = make_int2((int)0xFFFF0000u, 0);
        if (lane < nC) md = cmeta[c0 + lane];
        int nB = (nC + 7) & ~7;
        for (int b0 = 0; b0 < nB; b0 += 8) {
            float2 v[8]; int pj[8];
            #pragma unroll
            for (int j = 0; j < 8; ++j) {
                pj[j] = __builtin_amdgcn_readlane(md.x, b0 + j);
                int src = sbase + (pj[j] & 0xFFFF);
                v[j] = *(const float2*)&x[(size_t)((unsigned)src & gmask) * DD + lane * 2];
            }
            #pragma unroll
            for (int j = 0; j < 8; ++j) {
                int dst = sbase + (int)(((unsigned)pj[j]) >> 16);
                float w = __builtin_bit_cast(float, __builtin_amdgcn_readlane(md.y, b0 + j));
                if (dst != curRow) {
                    unsigned rl = (unsigned)(curRow - m0);
                    if (rl < 64u) {
                        atomicAdd(&sAcc[rl * DD + lane],      ax);
                        atomicAdd(&sAcc[rl * DD + 64 + lane], ay);
                    }
                    curRow = dst; ax = 0.f; ay = 0.f;
                }
                ax = fmaf(w, v[j].x, ax);
                ay = fmaf(w, v[j].y, ay);
            }
        }
    }
    {
        unsigned rl = (unsigned)(curRow - m0);
        if (rl < 64u) {
            atomicAdd(&sAcc[rl * DD + lane],      ax);
            atomicAdd(&sAcc[rl * DD + 64 + lane], ay);
        }
    }
    __syncthreads();

    // ---- in-place repack: fp32 -> bf16 hi/lo, XOR-swizzled ----
    float fe[8], fo[8];
    #pragma unroll
    for (int i = 0; i < 8; ++i) {
        int row = wave * 8 + i;
        fe[i] = sAcc[row * DD + lane];        // feature 2*lane
        fo[i] = sAcc[row * DD + 64 + lane];   // feature 2*lane+1
    }
    __syncthreads();
    #pragma unroll
    for (int i = 0; i < 8; ++i) {
        int row = wave * 8 + i;
        unsigned short hx = f2bf(fe[i]); unsigned short lx = f2bf(fe[i] - bf2f(hx));
        unsigned short hy = f2bf(fo[i]); unsigned short ly = f2bf(fo[i] - bf2f(hy));
        unsigned bo = ((unsigned)row * 256u + (unsigned)lane * 4u) ^ ((unsigned)(row & 7) << 4);
        *(unsigned*)(sH + bo) = ((unsigned)hy << 16) | hx;
        *(unsigned*)(sL + bo) = ((unsigned)ly << 16) | lx;
    }
    __syncthreads();

    // ---- MFMA phase: wave strip = rows 0..63, cols wave*16..+15 ----
    f32x4 acc[4];
    #pragma unroll
    for (int m = 0; m < 4; ++m) acc[m] = (f32x4){0.f, 0.f, 0.f, 0.f};

    #pragma unroll
    for (int ks = 0; ks < 4; ++ks) {
        #pragma unroll
        for (int m = 0; m < 4; ++m) {
            int row = m * 16 + n;
            unsigned bo = ((unsigned)row * 256u + (unsigned)(ks * 64 + kq * 16))
                          ^ ((unsigned)(row & 7) << 4);
            s16x8 ah = *(const s16x8*)(sH + bo);
            s16x8 al = *(const s16x8*)(sL + bo);
            acc[m] = __builtin_amdgcn_mfma_f32_16x16x32_bf16(ah, bh[ks], acc[m], 0, 0, 0);
            acc[m] = __builtin_amdgcn_mfma_f32_16x16x32_bf16(ah, bl[ks], acc[m], 0, 0, 0);
            acc[m] = __builtin_amdgcn_mfma_f32_16x16x32_bf16(al, bh[ks], acc[m], 0, 0, 0);
        }
    }
    __syncthreads();                     // all waves done reading sH/sL

    // ---- stage results: plain [64][128] fp32 (2-way bank alias = free) ----
    #pragma unroll
    for (int m = 0; m < 4; ++m) {
        #pragma unroll
        for (int r = 0; r < 4; ++r) {
            int row = m * 16 + kq * 4 + r;
            sAcc[row * DD + wave * 16 + n] = acc[m][r];
        }
    }
    __syncthreads();

    // ---- full-cacheline streamed store: bias + relu fused ----
    {
        const f32x4* sV = (const f32x4*)sBuf;
        f32x4* op = (f32x4*)&out[(size_t)m0 * DD];
        f32x4 bb = *(const f32x4*)&bias[(t & 31) * 4];   // col group invariant
        #pragma unroll
        for (int i = 0; i < 4; ++i) {
            int idx = i * 512 + t;                       // 0..2047 float4s
            f32x4 v = sV[idx];
            v[0] = fmaxf(v[0] + bb[0], 0.f);
            v[1] = fmaxf(v[1] + bb[1], 0.f);
            v[2] = fmaxf(v[2] + bb[2], 0.f);
            v[3] = fmaxf(v[3] + bb[3], 0.f);
            op[idx] = v;
        }
    }
}

// ---------- launch ----------

extern "C" void kernel_launch(void* const* d_in, const int* in_sizes, int n_in,
                              void* d_out, int out_size, void* d_ws, size_t ws_size,
                              hipStream_t stream) {
    const int*   ei  = (const int*)d_in[0];
    const float* emb = (const float*)d_in[1];
    const float* W1  = (const float*)d_in[2];
    const float* b1  = (const float*)d_in[3];
    const float* W2  = (const float*)d_in[4];
    const float* b2  = (const float*)d_in[5];
    const float* W3  = (const float*)d_in[6];
    const float* b3  = (const float*)d_in[7];
    float* out = (float*)d_out;

    float* x_mid = (float*)d_ws;                       // NN*DD floats (256 MiB)
    float* dinv  = x_mid + (size_t)NN * DD;
    int*   deg   = (int*)(dinv + NN);
    int*   coff  = deg + NN;
    int*   cur   = coff + NN;
    int2*  cmeta = (int2*)(cur + NN);                  // NE int2 (8 MiB)
    short* WTh1  = (short*)(cmeta + NE);
    short* WTl1  = WTh1 + DD * DD;
    short* WTh2  = WTl1 + DD * DD;
    short* WTl2  = WTh2 + DD * DD;
    short* WTh3  = WTl2 + DD * DD;
    short* WTl3  = WTh3 + DD * DD;

    hipMemsetAsync(deg, 0, NN * sizeof(int), stream);
    k_count<<<NE / 256, 256, 0, stream>>>(ei, deg);
    k_dinv<<<NN / 256, 256, 0, stream>>>(deg, dinv);
    k_scan<<<NB, NPN, 0, stream>>>(deg, coff, cur);
    k_fill<<<NE / 256, 256, 0, stream>>>(ei, dinv, coff, cur, cmeta);

    k_wsplit<<<64, 256, 0, stream>>>(W1, WTh1, WTl1);
    k_wsplit<<<64, 256, 0, stream>>>(W2, WTh2, WTl2);
    k_wsplit<<<64, 256, 0, stream>>>(W3, WTh3, WTl3);

    // layer 1: x = tiled emb (gmask folds node id onto the 1024-row table)
    k_layer<<<NN / 64, 512, 0, stream>>>(emb, NPN - 1, WTh1, WTl1, b1,
                                         dinv, coff, cmeta, out);
    // layer 2: out -> x_mid
    k_layer<<<NN / 64, 512, 0, stream>>>(out, 0xFFFFFFFFu, WTh2, WTl2, b2,
                                         dinv, coff, cmeta, x_mid);
    // layer 3: x_mid -> out
    k_layer<<<NN / 64, 512, 0, stream>>>(x_mid, 0xFFFFFFFFu, WTh3, WTl3, b3,
                                         dinv, coff, cmeta, out);
}

// Round 7
// 1151.004 us; speedup vs baseline: 1.0844x; 1.0844x over previous
//
#include <hip/hip_runtime.h>

#define NPN   1024            // nodes per slice
#define NB    512             // batch (slices)
#define NE_S  2048            // edges per slice
#define DD    128             // feature dim
#define NN    (NB * NPN)      // 524288 total nodes
#define NE    (NB * NE_S)     // 1048576 total edges

typedef short s16x8 __attribute__((ext_vector_type(8)));
typedef float f32x4 __attribute__((ext_vector_type(4)));

static __device__ __forceinline__ unsigned short f2bf(float f) {
    unsigned u = __builtin_bit_cast(unsigned, f);
    unsigned r = (u + 0x7FFFu + ((u >> 16) & 1u)) >> 16;   // RNE
    return (unsigned short)r;
}
static __device__ __forceinline__ float bf2f(unsigned short h) {
    unsigned u = ((unsigned)h) << 16;
    return __builtin_bit_cast(float, u);
}

// ---------- CSR / degree precompute (layer-invariant) ----------

__global__ void k_count(const int* __restrict__ ei, int* __restrict__ deg) {
    int t = blockIdx.x * 256 + threadIdx.x;          // 0..NE-1
    int b = t >> 11, e = t & (NE_S - 1);
    int col = ei[b * (2 * NE_S) + NE_S + e];
    atomicAdd(&deg[b * NPN + col], 1);
}

__global__ void k_dinv(const int* __restrict__ deg, float* __restrict__ dinv) {
    int i = blockIdx.x * 256 + threadIdx.x;
    dinv[i] = rsqrtf((float)(deg[i] + 1));           // +1 self-loop
}

__global__ __launch_bounds__(1024) void k_scan(const int* __restrict__ deg,
                                               int* __restrict__ coff,
                                               int* __restrict__ cur) {
    __shared__ int s[NPN];
    int b = blockIdx.x, t = threadIdx.x;
    int v = deg[b * NPN + t];
    s[t] = v;
    __syncthreads();
    for (int off = 1; off < NPN; off <<= 1) {
        int add = (t >= off) ? s[t - off] : 0;
        __syncthreads();
        s[t] += add;
        __syncthreads();
    }
    coff[b * NPN + t] = b * NE_S + (s[t] - v);       // exclusive prefix, global offset
    cur[b * NPN + t] = 0;
}

// packed edge meta: .x = src_local | (dst_local<<16), .y = bitcast(norm)
__global__ void k_fill(const int* __restrict__ ei, const float* __restrict__ dinv,
                       const int* __restrict__ coff, int* __restrict__ cur,
                       int2* __restrict__ cmeta) {
    int t = blockIdx.x * 256 + threadIdx.x;
    int b = t >> 11, e = t & (NE_S - 1);
    int r = ei[b * (2 * NE_S) + e];
    int c = ei[b * (2 * NE_S) + NE_S + e];
    int gr = b * NPN + r, gc = b * NPN + c;
    int pos = coff[gc] + atomicAdd(&cur[gc], 1);
    float nw = dinv[gr] * dinv[gc];
    cmeta[pos] = make_int2(r | (c << 16), __builtin_bit_cast(int, nw));
}

// ---------- W pre-transpose + bf16 hi/lo split (per layer, tiny) ----------

__global__ __launch_bounds__(256) void k_wsplit(const float* __restrict__ W,
                                                short* __restrict__ WTh,
                                                short* __restrict__ WTl) {
    int idx = blockIdx.x * 256 + threadIdx.x;        // 0..16383
    int k = idx >> 7, n = idx & 127;
    float f = W[idx];
    unsigned short h = f2bf(f);
    unsigned short l = f2bf(f - bf2f(h));
    WTh[n * DD + k] = (short)h;
    WTl[n * DD + k] = (short)l;
}

// ---------- fused GCN layer: out = relu((A_hat x) @ W + b) ----------
// 512 thr / 8 waves / block; 64x128 output tile; 32 KiB LDS union
//   (4 blocks/CU, 32 waves/CU):
//   phase A: fp32 accumulator sAcc[64][128], de-interleaved cols.
//   phase B: bf16 hi half [0,16K) + lo half [16K,32K), XOR-swizzled.
//   phase C: fp32 result staging [64][128] -> full-cacheline stores.
// B-fragments (W) are loaded INSIDE the MFMA ks-loop (8 VGPRs live, L2
// hits) instead of being preloaded across the gather: keeps peak VGPR
// pressure < 64 so __launch_bounds__(512,8) causes NO scratch spills
// (round 5/6 spilled ~320 MiB/dispatch of scratch traffic to HBM).
// Gather: wave w owns rows w*8..+7 and their contiguous CSR edge range;
// meta broadcast via v_readlane (scalar control), 8 row-loads in flight,
// run-based accumulation (edges dst-sorted) -> LDS add per run.

__global__ __launch_bounds__(512, 8) void k_layer(const float* __restrict__ x,
                                                  unsigned gmask,
                                                  const short* __restrict__ WTh,
                                                  const short* __restrict__ WTl,
                                                  const float* __restrict__ bias,
                                                  const float* __restrict__ dinv,
                                                  const int* __restrict__ coff,
                                                  const int2* __restrict__ cmeta,
                                                  float* __restrict__ out) {
    __shared__ float sBuf[64 * DD];      // 32 KiB union
    float* sAcc = sBuf;
    char*  sH   = (char*)sBuf;           // after repack: hi bytes [0,16K)
    char*  sL   = (char*)sBuf + 16384;   // lo bytes [16K,32K)

    int t = threadIdx.x;
    int wave = t >> 6, lane = t & 63;
    // XCD-aware swizzle: 8192 blocks = 8 XCDs x 1024; 16 consecutive
    // blocks (one slice) land on one XCD -> slice rows L2-hit.
    int wb = (int)((blockIdx.x & 7) * 1024 + (blockIdx.x >> 3));
    int m0 = wb * 64;
    int sbase = (wb >> 4) << 10;         // slice base node

    int n  = lane & 15;
    int kq = lane >> 4;

    // wave's CSR range (scalarized -> uniform control flow)
    int r0g = m0 + wave * 8;
    int eBeg = __builtin_amdgcn_readfirstlane(coff[r0g]);
    int eEnd = __builtin_amdgcn_readfirstlane((r0g + 8 < NN) ? coff[r0g + 8] : NE);

    // ---- self-loop init: rows wave*8..+7, lane covers features 2l,2l+1 ----
    {
        float2 sv[8]; float dvv[8];
        #pragma unroll
        for (int i = 0; i < 8; ++i) {
            int g = m0 + wave * 8 + i;
            dvv[i] = dinv[g];
            sv[i] = *(const float2*)&x[(size_t)((unsigned)g & gmask) * DD + lane * 2];
        }
        #pragma unroll
        for (int i = 0; i < 8; ++i) {
            int row = wave * 8 + i;
            float s = dvv[i] * dvv[i];
            sAcc[row * DD + lane]      = s * sv[i].x;
            sAcc[row * DD + 64 + lane] = s * sv[i].y;
        }
    }
    // no barrier needed: this wave only touches its own 8 rows below

    // ---- edge walk: run-based accumulation, 8 loads in flight ----
    float ax = 0.f, ay = 0.f;
    int curRow = -1;
    for (int c0 = eBeg; c0 < eEnd; c0 += 64) {
        int nC = eEnd - c0; nC = nC > 64 ? 64 : nC;
        // pad lanes: src10=0 (valid row, w=0), dst10=0xFFFF (run-breaker)
        int2 md = make_int2((int)0xFFFF0000u, 0);
        if (lane < nC) md = cmeta[c0 + lane];
        int nB = (nC + 7) & ~7;
        for (int b0 = 0; b0 < nB; b0 += 8) {
            float2 v[8]; int pj[8];
            #pragma unroll
            for (int j = 0; j < 8; ++j) {
                pj[j] = __builtin_amdgcn_readlane(md.x, b0 + j);
                int src = sbase + (pj[j] & 0xFFFF);
                v[j] = *(const float2*)&x[(size_t)((unsigned)src & gmask) * DD + lane * 2];
            }
            #pragma unroll
            for (int j = 0; j < 8; ++j) {
                int dst = sbase + (int)(((unsigned)pj[j]) >> 16);
                float w = __builtin_bit_cast(float, __builtin_amdgcn_readlane(md.y, b0 + j));
                if (dst != curRow) {
                    unsigned rl = (unsigned)(curRow - m0);
                    if (rl < 64u) {
                        atomicAdd(&sAcc[rl * DD + lane],      ax);
                        atomicAdd(&sAcc[rl * DD + 64 + lane], ay);
                    }
                    curRow = dst; ax = 0.f; ay = 0.f;
                }
                ax = fmaf(w, v[j].x, ax);
                ay = fmaf(w, v[j].y, ay);
            }
        }
    }
    {
        unsigned rl = (unsigned)(curRow - m0);
        if (rl < 64u) {
            atomicAdd(&sAcc[rl * DD + lane],      ax);
            atomicAdd(&sAcc[rl * DD + 64 + lane], ay);
        }
    }
    __syncthreads();

    // ---- in-place repack: fp32 -> bf16 hi/lo, XOR-swizzled ----
    float fe[8], fo[8];
    #pragma unroll
    for (int i = 0; i < 8; ++i) {
        int row = wave * 8 + i;
        fe[i] = sAcc[row * DD + lane];        // feature 2*lane
        fo[i] = sAcc[row * DD + 64 + lane];   // feature 2*lane+1
    }
    __syncthreads();
    #pragma unroll
    for (int i = 0; i < 8; ++i) {
        int row = wave * 8 + i;
        unsigned short hx = f2bf(fe[i]); unsigned short lx = f2bf(fe[i] - bf2f(hx));
        unsigned short hy = f2bf(fo[i]); unsigned short ly = f2bf(fo[i] - bf2f(hy));
        unsigned bo = ((unsigned)row * 256u + (unsigned)lane * 4u) ^ ((unsigned)(row & 7) << 4);
        *(unsigned*)(sH + bo) = ((unsigned)hy << 16) | hx;
        *(unsigned*)(sL + bo) = ((unsigned)ly << 16) | lx;
    }
    __syncthreads();

    // ---- MFMA phase: wave strip = rows 0..63, cols wave*16..+15 ----
    // B fragments loaded per-ks (8 VGPRs live, L2-resident 64 KB table)
    f32x4 acc[4];
    #pragma unroll
    for (int m = 0; m < 4; ++m) acc[m] = (f32x4){0.f, 0.f, 0.f, 0.f};

    const short* bhp = &WTh[(wave * 16 + n) * DD + kq * 8];
    const short* blp = &WTl[(wave * 16 + n) * DD + kq * 8];
    #pragma unroll
    for (int ks = 0; ks < 4; ++ks) {
        s16x8 bhv = *(const s16x8*)(bhp + ks * 32);
        s16x8 blv = *(const s16x8*)(blp + ks * 32);
        #pragma unroll
        for (int m = 0; m < 4; ++m) {
            int row = m * 16 + n;
            unsigned bo = ((unsigned)row * 256u + (unsigned)(ks * 64 + kq * 16))
                          ^ ((unsigned)(row & 7) << 4);
            s16x8 ah = *(const s16x8*)(sH + bo);
            s16x8 al = *(const s16x8*)(sL + bo);
            acc[m] = __builtin_amdgcn_mfma_f32_16x16x32_bf16(ah, bhv, acc[m], 0, 0, 0);
            acc[m] = __builtin_amdgcn_mfma_f32_16x16x32_bf16(ah, blv, acc[m], 0, 0, 0);
            acc[m] = __builtin_amdgcn_mfma_f32_16x16x32_bf16(al, bhv, acc[m], 0, 0, 0);
        }
    }
    __syncthreads();                     // all waves done reading sH/sL

    // ---- stage results: plain [64][128] fp32 (2-way bank alias = free) ----
    #pragma unroll
    for (int m = 0; m < 4; ++m) {
        #pragma unroll
        for (int r = 0; r < 4; ++r) {
            int row = m * 16 + kq * 4 + r;
            sAcc[row * DD + wave * 16 + n] = acc[m][r];
        }
    }
    __syncthreads();

    // ---- full-cacheline streamed store: bias + relu fused ----
    {
        const f32x4* sV = (const f32x4*)sBuf;
        f32x4* op = (f32x4*)&out[(size_t)m0 * DD];
        f32x4 bb = *(const f32x4*)&bias[(t & 31) * 4];   // col group invariant
        #pragma unroll
        for (int i = 0; i < 4; ++i) {
            int idx = i * 512 + t;                       // 0..2047 float4s
            f32x4 v = sV[idx];
            v[0] = fmaxf(v[0] + bb[0], 0.f);
            v[1] = fmaxf(v[1] + bb[1], 0.f);
            v[2] = fmaxf(v[2] + bb[2], 0.f);
            v[3] = fmaxf(v[3] + bb[3], 0.f);
            op[idx] = v;
        }
    }
}

// ---------- launch ----------

extern "C" void kernel_launch(void* const* d_in, const int* in_sizes, int n_in,
                              void* d_out, int out_size, void* d_ws, size_t ws_size,
                              hipStream_t stream) {
    const int*   ei  = (const int*)d_in[0];
    const float* emb = (const float*)d_in[1];
    const float* W1  = (const float*)d_in[2];
    const float* b1  = (const float*)d_in[3];
    const float* W2  = (const float*)d_in[4];
    const float* b2  = (const float*)d_in[5];
    const float* W3  = (const float*)d_in[6];
    const float* b3  = (const float*)d_in[7];
    float* out = (float*)d_out;

    float* x_mid = (float*)d_ws;                       // NN*DD floats (256 MiB)
    float* dinv  = x_mid + (size_t)NN * DD;
    int*   deg   = (int*)(dinv + NN);
    int*   coff  = deg + NN;
    int*   cur   = coff + NN;
    int2*  cmeta = (int2*)(cur + NN);                  // NE int2 (8 MiB)
    short* WTh1  = (short*)(cmeta + NE);
    short* WTl1  = WTh1 + DD * DD;
    short* WTh2  = WTl1 + DD * DD;
    short* WTl2  = WTh2 + DD * DD;
    short* WTh3  = WTl2 + DD * DD;
    short* WTl3  = WTh3 + DD * DD;

    hipMemsetAsync(deg, 0, NN * sizeof(int), stream);
    k_count<<<NE / 256, 256, 0, stream>>>(ei, deg);
    k_dinv<<<NN / 256, 256, 0, stream>>>(deg, dinv);
    k_scan<<<NB, NPN, 0, stream>>>(deg, coff, cur);
    k_fill<<<NE / 256, 256, 0, stream>>>(ei, dinv, coff, cur, cmeta);

    k_wsplit<<<64, 256, 0, stream>>>(W1, WTh1, WTl1);
    k_wsplit<<<64, 256, 0, stream>>>(W2, WTh2, WTl2);
    k_wsplit<<<64, 256, 0, stream>>>(W3, WTh3, WTl3);

    // layer 1: x = tiled emb (gmask folds node id onto the 1024-row table)
    k_layer<<<NN / 64, 512, 0, stream>>>(emb, NPN - 1, WTh1, WTl1, b1,
                                         dinv, coff, cmeta, out);
    // layer 2: out -> x_mid
    k_layer<<<NN / 64, 512, 0, stream>>>(out, 0xFFFFFFFFu, WTh2, WTl2, b2,
                                         dinv, coff, cmeta, x_mid);
    // layer 3: x_mid -> out
    k_layer<<<NN / 64, 512, 0, stream>>>(x_mid, 0xFFFFFFFFu, WTh3, WTl3, b3,
                                         dinv, coff, cmeta, out);
}

// Round 9
// 1122.674 us; speedup vs baseline: 1.1118x; 1.0252x over previous
//
#include <hip/hip_runtime.h>

#define NPN   1024            // nodes per slice
#define NB    512             // batch (slices)
#define NE_S  2048            // edges per slice
#define DD    128             // feature dim
#define NN    (NB * NPN)      // 524288 total nodes
#define NE    (NB * NE_S)     // 1048576 total edges

typedef short s16x8 __attribute__((ext_vector_type(8)));
typedef float f32x4 __attribute__((ext_vector_type(4)));

static __device__ __forceinline__ unsigned short f2bf(float f) {
    unsigned u = __builtin_bit_cast(unsigned, f);
    unsigned r = (u + 0x7FFFu + ((u >> 16) & 1u)) >> 16;   // RNE
    return (unsigned short)r;
}
static __device__ __forceinline__ float bf2f(unsigned short h) {
    unsigned u = ((unsigned)h) << 16;
    return __builtin_bit_cast(float, u);
}

// ---------- CSR / degree precompute (layer-invariant) ----------

__global__ void k_count(const int* __restrict__ ei, int* __restrict__ deg) {
    int t = blockIdx.x * 256 + threadIdx.x;          // 0..NE-1
    int b = t >> 11, e = t & (NE_S - 1);
    int col = ei[b * (2 * NE_S) + NE_S + e];
    atomicAdd(&deg[b * NPN + col], 1);
}

__global__ void k_dinv(const int* __restrict__ deg, float* __restrict__ dinv) {
    int i = blockIdx.x * 256 + threadIdx.x;
    dinv[i] = rsqrtf((float)(deg[i] + 1));           // +1 self-loop
}

__global__ __launch_bounds__(1024) void k_scan(const int* __restrict__ deg,
                                               int* __restrict__ coff,
                                               int* __restrict__ cur) {
    __shared__ int s[NPN];
    int b = blockIdx.x, t = threadIdx.x;
    int v = deg[b * NPN + t];
    s[t] = v;
    __syncthreads();
    for (int off = 1; off < NPN; off <<= 1) {
        int add = (t >= off) ? s[t - off] : 0;
        __syncthreads();
        s[t] += add;
        __syncthreads();
    }
    coff[b * NPN + t] = b * NE_S + (s[t] - v);       // exclusive prefix, global offset
    cur[b * NPN + t] = 0;
}

// packed edge meta: .x = src_local | (dst_local<<16), .y = bitcast(norm)
__global__ void k_fill(const int* __restrict__ ei, const float* __restrict__ dinv,
                       const int* __restrict__ coff, int* __restrict__ cur,
                       int2* __restrict__ cmeta) {
    int t = blockIdx.x * 256 + threadIdx.x;
    int b = t >> 11, e = t & (NE_S - 1);
    int r = ei[b * (2 * NE_S) + e];
    int c = ei[b * (2 * NE_S) + NE_S + e];
    int gr = b * NPN + r, gc = b * NPN + c;
    int pos = coff[gc] + atomicAdd(&cur[gc], 1);
    float nw = dinv[gr] * dinv[gc];
    cmeta[pos] = make_int2(r | (c << 16), __builtin_bit_cast(int, nw));
}

// ---------- W pre-transpose + bf16 hi/lo split (per layer, tiny) ----------

__global__ __launch_bounds__(256) void k_wsplit(const float* __restrict__ W,
                                                short* __restrict__ WTh,
                                                short* __restrict__ WTl) {
    int idx = blockIdx.x * 256 + threadIdx.x;        // 0..16383
    int k = idx >> 7, n = idx & 127;
    float f = W[idx];
    unsigned short h = f2bf(f);
    unsigned short l = f2bf(f - bf2f(h));
    WTh[n * DD + k] = (short)h;
    WTl[n * DD + k] = (short)l;
}

// ---------- fused GCN layer: out = relu((A_hat x) @ W + b) ----------
// 512 thr / 8 waves / block; 64x128 output tile; 32 KiB LDS union
//   (4 blocks/CU, 32 waves/CU):
//   phase A: fp32 accumulator sAcc[64][128], de-interleaved cols.
//   phase B: bf16 hi half [0,16K) + lo half [16K,32K), XOR-swizzled.
// Single-exposure edge walk: all 16 row-loads issued back-to-back
// (re-readlane at use), meta hoisted over self-init. Direct scatter
// epilogue (L2 merges the half-lines; r7 proved WRITE=ideal w/o spills).
// B fragments loaded per-ks inside MFMA loop: peak VGPR < 64, no spills.
// NOTE: curRow is SLICE-LOCAL (0..1023); the wave's rows start at
// wlo = (m0 - sbase) + wave*8 in slice-local coords — both flushes
// must use wlo (r8 bug: in-loop flush used wave*8 alone).

__global__ __launch_bounds__(512, 8) void k_layer(const float* __restrict__ x,
                                                  unsigned gmask,
                                                  const short* __restrict__ WTh,
                                                  const short* __restrict__ WTl,
                                                  const float* __restrict__ bias,
                                                  const float* __restrict__ dinv,
                                                  const int* __restrict__ coff,
                                                  const int2* __restrict__ cmeta,
                                                  float* __restrict__ out) {
    __shared__ float sBuf[64 * DD];      // 32 KiB union
    float* sAcc = sBuf;
    char*  sH   = (char*)sBuf;           // after repack: hi bytes [0,16K)
    char*  sL   = (char*)sBuf + 16384;   // lo bytes [16K,32K)

    int t = threadIdx.x;
    int wave = t >> 6, lane = t & 63;
    // XCD-aware swizzle: 8192 blocks = 8 XCDs x 1024; 16 consecutive
    // blocks (one slice) land on one XCD -> slice rows L2-hit.
    int wb = (int)((blockIdx.x & 7) * 1024 + (blockIdx.x >> 3));
    int m0 = wb * 64;
    int sbase = (wb >> 4) << 10;         // slice base node

    int n  = lane & 15;
    int kq = lane >> 4;

    // wave's CSR range (scalarized -> uniform control flow)
    int r0g = m0 + wave * 8;
    int wlo = (m0 - sbase) + wave * 8;   // slice-local first row of this wave
    int eBeg = __builtin_amdgcn_readfirstlane(coff[r0g]);
    int eEnd = __builtin_amdgcn_readfirstlane((r0g + 8 < NN) ? coff[r0g + 8] : NE);

    // ---- first meta chunk: issue EARLY so it overlaps self-init ----
    int c0 = eBeg;
    int nC0 = eEnd - c0; nC0 = nC0 > 64 ? 64 : nC0;
    int2 md = make_int2((int)0xFFFF0000u, 0);
    if (lane < nC0) md = cmeta[c0 + lane];

    // ---- self-loop init: rows wave*8..+7, lane covers features 2l,2l+1 ----
    {
        float2 sv[8]; float dvv[8];
        #pragma unroll
        for (int i = 0; i < 8; ++i) {
            int g = m0 + wave * 8 + i;
            dvv[i] = dinv[g];
            sv[i] = *(const float2*)&x[(size_t)((unsigned)g & gmask) * DD + lane * 2];
        }
        #pragma unroll
        for (int i = 0; i < 8; ++i) {
            int row = wave * 8 + i;
            float s = dvv[i] * dvv[i];
            sAcc[row * DD + lane]      = s * sv[i].x;
            sAcc[row * DD + 64 + lane] = s * sv[i].y;
        }
    }
    // no barrier needed: this wave only touches its own 8 rows below

    // ---- edge walk: batch-16 loads, run-based accumulation ----
    float ax = 0.f, ay = 0.f;
    int curRow = -1;
    int nC = nC0;
    while (true) {
        int nB = (nC + 15) & ~15;
        for (int b0 = 0; b0 < nB; b0 += 16) {
            float2 v[16];
            #pragma unroll
            for (int j = 0; j < 16; ++j) {
                int sj = __builtin_amdgcn_readlane(md.x, b0 + j) & 0xFFFF;
                v[j] = *(const float2*)&x[(size_t)((unsigned)(sbase + sj) & gmask) * DD + lane * 2];
            }
            #pragma unroll
            for (int j = 0; j < 16; ++j) {
                int pj = __builtin_amdgcn_readlane(md.x, b0 + j);
                int dst = (int)(((unsigned)pj) >> 16);       // slice-local, pad=0xFFFF
                float w = __builtin_bit_cast(float, __builtin_amdgcn_readlane(md.y, b0 + j));
                if (dst != curRow) {
                    unsigned rl = (unsigned)(curRow - wlo);
                    if (rl < 8u) {
                        int row = wave * 8 + (int)rl;
                        atomicAdd(&sAcc[row * DD + lane],      ax);
                        atomicAdd(&sAcc[row * DD + 64 + lane], ay);
                    }
                    curRow = dst; ax = 0.f; ay = 0.f;
                }
                ax = fmaf(w, v[j].x, ax);
                ay = fmaf(w, v[j].y, ay);
            }
        }
        c0 += 64;
        if (c0 >= eEnd) break;
        nC = eEnd - c0; nC = nC > 64 ? 64 : nC;
        md = make_int2((int)0xFFFF0000u, 0);
        if (lane < nC) md = cmeta[c0 + lane];
    }
    {
        unsigned rl = (unsigned)(curRow - wlo);
        if (rl < 8u) {
            int row = wave * 8 + (int)rl;
            atomicAdd(&sAcc[row * DD + lane],      ax);
            atomicAdd(&sAcc[row * DD + 64 + lane], ay);
        }
    }
    __syncthreads();

    // ---- in-place repack: fp32 -> bf16 hi/lo, XOR-swizzled ----
    float fe[8], fo[8];
    #pragma unroll
    for (int i = 0; i < 8; ++i) {
        int row = wave * 8 + i;
        fe[i] = sAcc[row * DD + lane];        // feature 2*lane
        fo[i] = sAcc[row * DD + 64 + lane];   // feature 2*lane+1
    }
    __syncthreads();
    #pragma unroll
    for (int i = 0; i < 8; ++i) {
        int row = wave * 8 + i;
        unsigned short hx = f2bf(fe[i]); unsigned short lx = f2bf(fe[i] - bf2f(hx));
        unsigned short hy = f2bf(fo[i]); unsigned short ly = f2bf(fo[i] - bf2f(hy));
        unsigned bo = ((unsigned)row * 256u + (unsigned)lane * 4u) ^ ((unsigned)(row & 7) << 4);
        *(unsigned*)(sH + bo) = ((unsigned)hy << 16) | hx;
        *(unsigned*)(sL + bo) = ((unsigned)ly << 16) | lx;
    }
    __syncthreads();

    // ---- MFMA phase: wave strip = rows 0..63, cols wave*16..+15 ----
    // B fragments loaded per-ks (8 VGPRs live, L2-resident 64 KB table)
    f32x4 acc[4];
    #pragma unroll
    for (int m = 0; m < 4; ++m) acc[m] = (f32x4){0.f, 0.f, 0.f, 0.f};

    const short* bhp = &WTh[(wave * 16 + n) * DD + kq * 8];
    const short* blp = &WTl[(wave * 16 + n) * DD + kq * 8];
    #pragma unroll
    for (int ks = 0; ks < 4; ++ks) {
        s16x8 bhv = *(const s16x8*)(bhp + ks * 32);
        s16x8 blv = *(const s16x8*)(blp + ks * 32);
        #pragma unroll
        for (int m = 0; m < 4; ++m) {
            int row = m * 16 + n;
            unsigned bo = ((unsigned)row * 256u + (unsigned)(ks * 64 + kq * 16))
                          ^ ((unsigned)(row & 7) << 4);
            s16x8 ah = *(const s16x8*)(sH + bo);
            s16x8 al = *(const s16x8*)(sL + bo);
            acc[m] = __builtin_amdgcn_mfma_f32_16x16x32_bf16(ah, bhv, acc[m], 0, 0, 0);
            acc[m] = __builtin_amdgcn_mfma_f32_16x16x32_bf16(ah, blv, acc[m], 0, 0, 0);
            acc[m] = __builtin_amdgcn_mfma_f32_16x16x32_bf16(al, bhv, acc[m], 0, 0, 0);
        }
    }

    // ---- direct epilogue: bias + relu; C/D layout col=lane&15, row=kq*4+reg ----
    int col = wave * 16 + n;
    float bv = bias[col];
    #pragma unroll
    for (int m = 0; m < 4; ++m) {
        #pragma unroll
        for (int r = 0; r < 4; ++r) {
            int row = m * 16 + kq * 4 + r;
            float vv = acc[m][r] + bv;
            out[(size_t)(m0 + row) * DD + col] = fmaxf(vv, 0.f);
        }
    }
}

// ---------- launch ----------

extern "C" void kernel_launch(void* const* d_in, const int* in_sizes, int n_in,
                              void* d_out, int out_size, void* d_ws, size_t ws_size,
                              hipStream_t stream) {
    const int*   ei  = (const int*)d_in[0];
    const float* emb = (const float*)d_in[1];
    const float* W1  = (const float*)d_in[2];
    const float* b1  = (const float*)d_in[3];
    const float* W2  = (const float*)d_in[4];
    const float* b2  = (const float*)d_in[5];
    const float* W3  = (const float*)d_in[6];
    const float* b3  = (const float*)d_in[7];
    float* out = (float*)d_out;

    float* x_mid = (float*)d_ws;                       // NN*DD floats (256 MiB)
    float* dinv  = x_mid + (size_t)NN * DD;
    int*   deg   = (int*)(dinv + NN);
    int*   coff  = deg + NN;
    int*   cur   = coff + NN;
    int2*  cmeta = (int2*)(cur + NN);                  // NE int2 (8 MiB)
    short* WTh1  = (short*)(cmeta + NE);
    short* WTl1  = WTh1 + DD * DD;
    short* WTh2  = WTl1 + DD * DD;
    short* WTl2  = WTh2 + DD * DD;
    short* WTh3  = WTl2 + DD * DD;
    short* WTl3  = WTh3 + DD * DD;

    hipMemsetAsync(deg, 0, NN * sizeof(int), stream);
    k_count<<<NE / 256, 256, 0, stream>>>(ei, deg);
    k_dinv<<<NN / 256, 256, 0, stream>>>(deg, dinv);
    k_scan<<<NB, NPN, 0, stream>>>(deg, coff, cur);
    k_fill<<<NE / 256, 256, 0, stream>>>(ei, dinv, coff, cur, cmeta);

    k_wsplit<<<64, 256, 0, stream>>>(W1, WTh1, WTl1);
    k_wsplit<<<64, 256, 0, stream>>>(W2, WTh2, WTl2);
    k_wsplit<<<64, 256, 0, stream>>>(W3, WTh3, WTl3);

    // layer 1: x = tiled emb (gmask folds node id onto the 1024-row table)
    k_layer<<<NN / 64, 512, 0, stream>>>(emb, NPN - 1, WTh1, WTl1, b1,
                                         dinv, coff, cmeta, out);
    // layer 2: out -> x_mid
    k_layer<<<NN / 64, 512, 0, stream>>>(out, 0xFFFFFFFFu, WTh2, WTl2, b2,
                                         dinv, coff, cmeta, x_mid);
    // layer 3: x_mid -> out
    k_layer<<<NN / 64, 512, 0, stream>>>(x_mid, 0xFFFFFFFFu, WTh3, WTl3, b3,
                                         dinv, coff, cmeta, out);
}